// Round 6
// baseline (389.855 us; speedup 1.0000x reference)
//
#include <hip/hip_runtime.h>
#include <stdint.h>

// FeatureQuantizer: VQ-VAE quantize forward.
// inputs (32,256,32,32) f32, embed (256,1024) f32.
// out = [ quantize (B,C,H,W) 8388608 | loss 1 | onehot (32768,1024) 33554432 ] f32
//
// R5 -> R6:
//  * gemm: revert to R4 3-buffer structure, plain launch_bounds(256).
//    R5's (256,4) capped total regs at 128 -> fragment spill (WRITE 3.3->64.7MB).
//  * pipeline 7 -> 4 dispatches: memset(4KB) -> kq_prep (prep_e+prep_x fused)
//    -> kq_gemm -> kq_finale (combine + inline fp64 refine + quantize gather +
//    onehot zero/scatter + loss via done-counter).

#define NROWS 32768
#define OUT0  8388608
#define TAU   0.01f
#define RCAP  8192

typedef __attribute__((ext_vector_type(8))) short short8;
typedef __attribute__((ext_vector_type(4))) float floatx4;

__device__ __forceinline__ void gload16(const void* g, void* l) {
    __builtin_amdgcn_global_load_lds(
        (const __attribute__((address_space(1))) void*)g,
        (__attribute__((address_space(3))) void*)l, 16, 0, 0);
}
__device__ __forceinline__ unsigned short bf16_rn(float x) {
    union { float f; unsigned u; } v; v.f = x;
    unsigned r = v.u + 0x7FFF + ((v.u >> 16) & 1);
    return (unsigned short)(r >> 16);
}
__device__ __forceinline__ float bf16_f(unsigned short h) {
    union { unsigned u; float f; } v; v.u = ((unsigned)h) << 16;
    return v.f;
}

// ---- P: fused prep. blocks [0,512): inputs->Ahi/Alo/xnorm ; [512,576): embed->Bcat/enorm
__global__ __launch_bounds__(256) void kq_prep(
    const float* __restrict__ inp, const float* __restrict__ embed,
    unsigned short* __restrict__ Ahi, unsigned short* __restrict__ Alo,
    unsigned short* __restrict__ Bcat, float* __restrict__ enorm,
    float* __restrict__ xnorm) {
    __shared__ float ls[64][65];
    __shared__ float sums[16][64];
    int t = threadIdx.x;
    if (blockIdx.x >= 512) {
        // ---- embed path ----
        int bx = blockIdx.x - 512;    // 64 = 16 kt * 4 ct
        int ct = bx & 3, kt = bx >> 2;
        int c0 = ct * 64, k0 = kt * 64;
#pragma unroll
        for (int p = 0; p < 16; ++p) {
            int cl = p * 4 + (t >> 6);
            int kl = t & 63;
            ls[cl][kl] = embed[(size_t)(c0 + cl) * 1024 + k0 + kl];
        }
        __syncthreads();
#pragma unroll
        for (int p = 0; p < 16; ++p) {
            int kl = p * 4 + (t >> 6);
            int c = t & 63;
            float x = ls[c][kl];
            unsigned short hi = bf16_rn(x);
            unsigned short lo = bf16_rn(x - bf16_f(hi));
            size_t base = (size_t)(k0 + kl) * 512;
            Bcat[base + c0 + c]       = hi;
            Bcat[base + 256 + c0 + c] = lo;
        }
        if (t < 64) {
            float s = 0.f;
#pragma unroll 8
            for (int c = 0; c < 64; ++c) {
                float e = ls[c][t];
                s = fmaf(e, e, s);
            }
            atomicAdd(enorm + k0 + t, s);
        }
        return;
    }
    // ---- inputs path ----
    int bx = blockIdx.x;          // 512 = 32 b * 16 hwt
    int hwt = bx & 15;
    int b   = bx >> 4;
    int hw0 = hwt * 64;
    float xpart[4] = {0.f, 0.f, 0.f, 0.f};
    for (int ct = 0; ct < 4; ++ct) {
        const float* src = inp + ((size_t)b << 18) + (size_t)(ct * 64) * 1024 + hw0;
        __syncthreads();          // ls reuse across ct
#pragma unroll
        for (int p = 0; p < 4; ++p) {
            int cl = (t >> 4) + p * 16;
            int h4 = (t & 15) << 2;
            float4 v = *(const float4*)(src + (size_t)cl * 1024 + h4);
            ls[cl][h4] = v.x; ls[cl][h4+1] = v.y; ls[cl][h4+2] = v.z; ls[cl][h4+3] = v.w;
        }
        __syncthreads();
#pragma unroll
        for (int p = 0; p < 4; ++p) {
            int hwl = p * 16 + (t >> 4);
            int c4 = (t & 15) << 2;
            float x0 = ls[c4][hwl], x1 = ls[c4+1][hwl];
            float x2 = ls[c4+2][hwl], x3 = ls[c4+3][hwl];
            ushort4 hi, lo;
            hi.x = bf16_rn(x0); lo.x = bf16_rn(x0 - bf16_f(hi.x));
            hi.y = bf16_rn(x1); lo.y = bf16_rn(x1 - bf16_f(hi.y));
            hi.z = bf16_rn(x2); lo.z = bf16_rn(x2 - bf16_f(hi.z));
            hi.w = bf16_rn(x3); lo.w = bf16_rn(x3 - bf16_f(hi.w));
            size_t n = ((size_t)b << 10) + hw0 + hwl;
            *(ushort4*)(Ahi + n * 256 + ct * 64 + c4) = hi;
            *(ushort4*)(Alo + n * 256 + ct * 64 + c4) = lo;
            xpart[p] = fmaf(x0, x0, xpart[p]);
            xpart[p] = fmaf(x1, x1, xpart[p]);
            xpart[p] = fmaf(x2, x2, xpart[p]);
            xpart[p] = fmaf(x3, x3, xpart[p]);
        }
    }
    __syncthreads();
#pragma unroll
    for (int p = 0; p < 4; ++p)
        sums[t & 15][p * 16 + (t >> 4)] = xpart[p];
    __syncthreads();
    if (t < 64) {
        float s = 0.f;
#pragma unroll
        for (int j = 0; j < 16; ++j) s += sums[j][t];
        xnorm[((size_t)b << 10) + hw0 + t] = s;
    }
}

// ---------------- K2: MFMA dist-GEMM + per-block top-2 argmin ----------------
// R4 structure: 3 LDS buffers; phase1 {A_hi, B_hi, B_lo} 64 MFMA/stage;
// phase2 {A_lo, B_hi} 32 MFMA/stage. Plain launch_bounds: no spill (VGPR ~112).
__global__ __launch_bounds__(256) void kq_gemm(
    const unsigned short* __restrict__ Ahi, const unsigned short* __restrict__ Alo,
    const unsigned short* __restrict__ Bcat, const float* __restrict__ enorm,
    float* __restrict__ gm1, float* __restrict__ gm2, int* __restrict__ gk) {

    __shared__ __align__(16) unsigned short As[128 * 64];    // 16 KB
    __shared__ __align__(16) unsigned short Bs[128 * 64];    // 16 KB
    __shared__ __align__(16) unsigned short Bs2[128 * 64];   // 16 KB
    __shared__ float cm1[2][128];
    __shared__ float cm2[2][128];
    __shared__ int   ckk[2][128];

    const int t = threadIdx.x;
    const int lane = t & 63, w = t >> 6;
    const int wm = w >> 1, wn = w & 1;
    // XCD swizzle: same rb -> same blockIdx%8 -> same XCD L2 holds the A-tile
    const int cb = blockIdx.x >> 8, rb = blockIdx.x & 255;

    const int l7 = lane & 7, l8 = lane >> 3;
    const int swz = l7 ^ l8;              // global-side k-group permutation

    floatx4 acc[4][4];
#pragma unroll
    for (int i = 0; i < 4; ++i)
#pragma unroll
        for (int j = 0; j < 4; ++j) acc[i][j] = (floatx4){0.f, 0.f, 0.f, 0.f};

    unsigned short* AsW  = As  + (w * 32) * 64;
    unsigned short* BsW  = Bs  + (w * 32) * 64;
    unsigned short* Bs2W = Bs2 + (w * 32) * 64;

    // ---- phase 1: A_hi x {B_hi, B_lo} ----
    for (int ci = 0; ci < 4; ++ci) {
        const unsigned short* Asrc = Ahi + (size_t)ci * 64;
        const unsigned short* B1 = Bcat + (size_t)ci * 64;          // e_hi chunk
        const unsigned short* B2 = Bcat + (size_t)(4 + ci) * 64;    // e_lo chunk
        __syncthreads();
#pragma unroll
        for (int i = 0; i < 4; ++i) {
            int arow = rb * 128 + w * 32 + i * 8 + l8;
            gload16(Asrc + (size_t)arow * 256 + swz * 8, AsW + (i * 8) * 64);
            int brow = cb * 128 + w * 32 + i * 8 + l8;
            gload16(B1 + (size_t)brow * 512 + swz * 8, BsW + (i * 8) * 64);
            gload16(B2 + (size_t)brow * 512 + swz * 8, Bs2W + (i * 8) * 64);
        }
        __syncthreads();
#pragma unroll
        for (int kk = 0; kk < 2; ++kk) {
            short8 af[4], bf[4], bf2[4];
            int pg = (kk * 4 + (lane >> 4)) ^ l7;
#pragma unroll
            for (int i = 0; i < 4; ++i) {
                int m = wm * 64 + i * 16 + (lane & 15);
                af[i] = *(const short8*)(As + m * 64 + pg * 8);
                int n = wn * 64 + i * 16 + (lane & 15);
                bf[i]  = *(const short8*)(Bs  + n * 64 + pg * 8);
                bf2[i] = *(const short8*)(Bs2 + n * 64 + pg * 8);
            }
#pragma unroll
            for (int i = 0; i < 4; ++i)
#pragma unroll
                for (int j = 0; j < 4; ++j) {
                    acc[i][j] = __builtin_amdgcn_mfma_f32_16x16x32_bf16(
                        af[i], bf[j], acc[i][j], 0, 0, 0);
                    acc[i][j] = __builtin_amdgcn_mfma_f32_16x16x32_bf16(
                        af[i], bf2[j], acc[i][j], 0, 0, 0);
                }
        }
    }
    // ---- phase 2: A_lo x B_hi ----
    for (int ci = 0; ci < 4; ++ci) {
        const unsigned short* Asrc = Alo + (size_t)ci * 64;
        const unsigned short* B1 = Bcat + (size_t)ci * 64;
        __syncthreads();
#pragma unroll
        for (int i = 0; i < 4; ++i) {
            int arow = rb * 128 + w * 32 + i * 8 + l8;
            gload16(Asrc + (size_t)arow * 256 + swz * 8, AsW + (i * 8) * 64);
            int brow = cb * 128 + w * 32 + i * 8 + l8;
            gload16(B1 + (size_t)brow * 512 + swz * 8, BsW + (i * 8) * 64);
        }
        __syncthreads();
#pragma unroll
        for (int kk = 0; kk < 2; ++kk) {
            short8 af[4], bf[4];
            int pg = (kk * 4 + (lane >> 4)) ^ l7;
#pragma unroll
            for (int i = 0; i < 4; ++i) {
                int m = wm * 64 + i * 16 + (lane & 15);
                af[i] = *(const short8*)(As + m * 64 + pg * 8);
                int n = wn * 64 + i * 16 + (lane & 15);
                bf[i] = *(const short8*)(Bs + n * 64 + pg * 8);
            }
#pragma unroll
            for (int i = 0; i < 4; ++i)
#pragma unroll
                for (int j = 0; j < 4; ++j)
                    acc[i][j] = __builtin_amdgcn_mfma_f32_16x16x32_bf16(
                        af[i], bf[j], acc[i][j], 0, 0, 0);
        }
    }

    // ---- epilogue: score = enorm[k] - 2*dot; top-2 per row ----
    float en[4];
#pragma unroll
    for (int j = 0; j < 4; ++j)
        en[j] = enorm[cb * 128 + wn * 64 + j * 16 + (lane & 15)];

    const int q4 = lane >> 4;
#pragma unroll
    for (int i = 0; i < 4; ++i) {
#pragma unroll
        for (int r = 0; r < 4; ++r) {
            float m1 = 3.4e38f, m2 = 3.4e38f; int k1 = 0x7fffffff;
#pragma unroll
            for (int j = 0; j < 4; ++j) {
                float s = fmaf(-2.f, acc[i][j][r], en[j]);
                int kg = cb * 128 + wn * 64 + j * 16 + (lane & 15);
                if (s < m1) { m2 = m1; m1 = s; k1 = kg; }
                else if (s < m2) m2 = s;
            }
#pragma unroll
            for (int d = 1; d < 16; d <<= 1) {   // 16-lane butterfly (cols)
                float om1 = __shfl_xor(m1, d, 64);
                float om2 = __shfl_xor(m2, d, 64);
                int   ok1 = __shfl_xor(k1, d, 64);
                if (om1 < m1 || (om1 == m1 && ok1 < k1)) {
                    m2 = fminf(m1, om2); m1 = om1; k1 = ok1;
                } else {
                    m2 = fminf(m2, om1);
                }
            }
            if ((lane & 15) == 0) {
                int row = wm * 64 + i * 16 + q4 * 4 + r;
                cm1[wn][row] = m1; cm2[wn][row] = m2; ckk[wn][row] = k1;
            }
        }
    }
    __syncthreads();
    if (t < 128) {
        float a1 = cm1[0][t], a2 = cm2[0][t]; int ak = ckk[0][t];
        float b1 = cm1[1][t], b2 = cm2[1][t]; int bk = ckk[1][t];
        if (b1 < a1 || (b1 == a1 && bk < ak)) { a2 = fminf(a1, b2); a1 = b1; ak = bk; }
        else { a2 = fminf(a2, b1); }
        size_t o = (size_t)cb * NROWS + (size_t)rb * 128 + t;
        gm1[o] = a1; gm2[o] = a2; gk[o] = ak;
    }
}

// ---- FINALE: combine + inline fp64 refine + quantize gather + onehot + loss --
// 512 blocks x 64 rows. Block owns rows r0..r0+63 (same b, hw0..hw0+63).
__global__ __launch_bounds__(256) void kq_finale(
    const float* __restrict__ inp, const float* __restrict__ embed,
    const float* __restrict__ gm1, const float* __restrict__ gm2,
    const int* __restrict__ gk, const float* __restrict__ xnorm,
    float* __restrict__ lossAcc, int* __restrict__ doneCnt,
    float* __restrict__ out0, float* __restrict__ onehot,
    float* __restrict__ lossOut) {

    __shared__ int    skk[64];       // final idx per local row
    __shared__ float  red[64];
    __shared__ int    flag[64];
    __shared__ int    nflag;
    __shared__ double xsh[256];
    __shared__ double ms[256];
    __shared__ int    ks[256];

    const int t = threadIdx.x;
    const int r0 = blockIdx.x * 64;
    const int b = r0 >> 10, hw0 = r0 & 1023;

    if (t == 0) nflag = 0;
    __syncthreads();

    if (t < 64) {
        int r = r0 + t;
        float a1 = gm1[r], a2 = gm2[r]; int ak = gk[r];
#pragma unroll
        for (int cbi = 1; cbi < 8; ++cbi) {
            size_t o = (size_t)cbi * NROWS + r;
            float b1 = gm1[o], b2 = gm2[o]; int bk = gk[o];
            if (b1 < a1 || (b1 == a1 && bk < ak)) { a2 = fminf(a1, b2); a1 = b1; ak = bk; }
            else { a2 = fminf(a2, b1); }
        }
        skk[t] = ak;
        red[t] = a1 + xnorm[r];
        if (a2 - a1 < TAU) {
            int p = atomicAdd(&nflag, 1);
            flag[p] = t;
        }
    }
    __syncthreads();

    // ---- inline fp64 re-resolve of near-tie rows (block-local, rare) ----
    for (int fi = 0; fi < nflag; ++fi) {
        int row = flag[fi];
        int hw = hw0 + row;
        xsh[t] = (double)inp[(((size_t)b << 8) + t) * 1024 + hw];
        __syncthreads();
        double s0 = 0.0, s1 = 0.0, s2 = 0.0, s3 = 0.0;
        const float* eb = embed + t;
#pragma unroll 4
        for (int c = 0; c < 256; ++c) {
            double xc2 = 2.0 * xsh[c];
            const float* er = eb + ((size_t)c << 10);
            double e0 = (double)er[0];
            double e1 = (double)er[256];
            double e2 = (double)er[512];
            double e3 = (double)er[768];
            s0 = fma(e0, e0 - xc2, s0);
            s1 = fma(e1, e1 - xc2, s1);
            s2 = fma(e2, e2 - xc2, s2);
            s3 = fma(e3, e3 - xc2, s3);
        }
        double bv = s0; int bk = t;
        if (s1 < bv) { bv = s1; bk = t + 256; }
        if (s2 < bv) { bv = s2; bk = t + 512; }
        if (s3 < bv) { bv = s3; bk = t + 768; }
        ms[t] = bv; ks[t] = bk;
        __syncthreads();
        if (t < 32) {
            double av = ms[t]; int ak = ks[t];
            for (int u = t + 32; u < 256; u += 32)
                if (ms[u] < av || (ms[u] == av && ks[u] < ak)) { av = ms[u]; ak = ks[u]; }
            ms[t] = av; ks[t] = ak;
        }
        __syncthreads();
        if (t == 0) {
            double av = ms[0]; int ak = ks[0];
            for (int u = 1; u < 32; ++u)
                if (ms[u] < av || (ms[u] == av && ks[u] < ak)) { av = ms[u]; ak = ks[u]; }
            skk[row] = ak;
        }
        __syncthreads();
    }

    // ---- quantize output: out0[b][c][hw0 + (t&63)] for all 256 c ----
    {
        const int hwl = t & 63;
        const int myk = skk[hwl];
        const int cg = t >> 6;
#pragma unroll 4
        for (int cc = 0; cc < 64; ++cc) {
            int c = cc * 4 + cg;
            out0[(((size_t)b << 8) + c) * 1024 + hw0 + hwl] =
                embed[((size_t)c << 10) + myk];
        }
    }

    // ---- onehot rows (zero + scatter in one pass) ----
    {
        float* dst = onehot + (size_t)r0 * 1024 + (t << 2);
#pragma unroll 4
        for (int row = 0; row < 64; ++row) {
            int k = skk[row];
            float4 v = make_float4(0.f, 0.f, 0.f, 0.f);
            if ((k >> 2) == t) ((float*)&v)[k & 3] = 1.0f;
            *(float4*)(dst + (size_t)row * 1024) = v;
        }
    }

    // ---- loss: block partial -> atomic; last block writes the scalar ----
    __syncthreads();
    if (t == 0) {
        float s = 0.f;
#pragma unroll
        for (int i = 0; i < 64; ++i) s += red[i];
        atomicAdd(lossAcc, s);
        __threadfence();
        int pos = atomicAdd(doneCnt, 1);
        if (pos == 511) {
            __threadfence();
            *lossOut = 1.25f * (*(volatile float*)lossAcc) / 8388608.0f;
        }
    }
}

// ======== Fallback path (ws too small for MFMA scratch) ========
__global__ void kq_norms(const float* __restrict__ embed, float* __restrict__ enorm,
                         float* __restrict__ lossAcc, int* __restrict__ rcount) {
    int k = blockIdx.x * 256 + threadIdx.x;
    float s = 0.f;
    for (int c = 0; c < 256; ++c) {
        float e = embed[(c << 10) + k];
        s = fmaf(e, e, s);
    }
    enorm[k] = s;
    if (k == 0) { *lossAcc = 0.f; *rcount = 0; }
}

__global__ __launch_bounds__(256) void kq_argmin(
    const float* __restrict__ inp, const float* __restrict__ embed,
    const float* __restrict__ enorm, int* __restrict__ idx_out,
    int* __restrict__ rcount, int* __restrict__ rlist) {
    __shared__ float xs[32][64];
    __shared__ float es[32][256];
    const int t  = threadIdx.x;
    const int tx = t & 31, ty = t >> 5;
    const int bi = blockIdx.x;
    const int b   = bi >> 4;
    const int hw0 = (bi & 15) << 6;
    const float* xbase = inp + ((size_t)b << 18) + hw0;
    float m1[8], m2[8]; int bk[8];
#pragma unroll
    for (int i = 0; i < 8; ++i) { m1[i] = 3.4e38f; m2[i] = 3.4e38f; bk[i] = 0; }
    for (int kt = 0; kt < 4; ++kt) {
        float acc[8][8];
#pragma unroll
        for (int i = 0; i < 8; ++i)
#pragma unroll
            for (int j = 0; j < 8; ++j) acc[i][j] = 0.f;
        for (int cc = 0; cc < 8; ++cc) {
            __syncthreads();
            {
                int r4 = (t & 15) << 2;
                int cbk = t >> 4;
#pragma unroll
                for (int p = 0; p < 2; ++p) {
                    int cl = cbk + (p << 4);
                    float4 v = *(const float4*)(xbase + (size_t)(cc * 32 + cl) * 1024 + r4);
                    *(float4*)&xs[cl][r4] = v;
                }
            }
            {
                int k4 = (t & 63) << 2;
                int cbk = t >> 6;
#pragma unroll
                for (int p = 0; p < 8; ++p) {
                    int cl = cbk + (p << 2);
                    float4 v = *(const float4*)(embed + (size_t)(cc * 32 + cl) * 1024 + kt * 256 + k4);
                    *(float4*)&es[cl][k4] = v;
                }
            }
            __syncthreads();
#pragma unroll 4
            for (int c = 0; c < 32; ++c) {
                float4 xa = *(const float4*)&xs[c][ty << 3];
                float4 xb = *(const float4*)&xs[c][(ty << 3) + 4];
                float4 ea = *(const float4*)&es[c][tx << 3];
                float4 eb = *(const float4*)&es[c][(tx << 3) + 4];
                float xv[8] = {xa.x, xa.y, xa.z, xa.w, xb.x, xb.y, xb.z, xb.w};
                float ev[8] = {ea.x, ea.y, ea.z, ea.w, eb.x, eb.y, eb.z, eb.w};
#pragma unroll
                for (int i = 0; i < 8; ++i)
#pragma unroll
                    for (int j = 0; j < 8; ++j)
                        acc[i][j] = fmaf(xv[i], ev[j], acc[i][j]);
            }
        }
        const float* en = enorm + kt * 256 + (tx << 3);
        float4 en0 = *(const float4*)en;
        float4 en1 = *(const float4*)(en + 4);
        float env[8] = {en0.x, en0.y, en0.z, en0.w, en1.x, en1.y, en1.z, en1.w};
        int kbase = kt * 256 + (tx << 3);
#pragma unroll
        for (int i = 0; i < 8; ++i) {
#pragma unroll
            for (int j = 0; j < 8; ++j) {
                float s = fmaf(-2.f, acc[i][j], env[j]);
                if (s < m1[i]) { m2[i] = m1[i]; m1[i] = s; bk[i] = kbase + j; }
                else if (s < m2[i]) m2[i] = s;
            }
        }
    }
    __syncthreads();
    float* r1 = &es[0][0];
    float* r2 = r1 + 2048;
    int*   rb = (int*)(r2 + 2048);
#pragma unroll
    for (int i = 0; i < 8; ++i) {
        int row = (ty << 3) + i;
        r1[row * 32 + tx] = m1[i];
        r2[row * 32 + tx] = m2[i];
        rb[row * 32 + tx] = bk[i];
    }
    __syncthreads();
    if (t < 64) {
        int row = t;
        float a1 = r1[row * 32], a2 = r2[row * 32];
        int   ab = rb[row * 32];
        for (int u = 1; u < 32; ++u) {
            float b1 = r1[row * 32 + u], b2 = r2[row * 32 + u];
            int   bb = rb[row * 32 + u];
            if (b1 < a1) { a2 = fminf(a1, b2); a1 = b1; ab = bb; }
            else         { a2 = fminf(a2, b1); }
        }
        int n = (b << 10) + hw0 + row;
        idx_out[n] = ab;
        if (a2 - a1 < TAU) {
            int pos = atomicAdd(rcount, 1);
            if (pos < RCAP) rlist[pos] = n;
        }
    }
}

__global__ __launch_bounds__(256) void kq_refine(
    const float* __restrict__ inp, const float* __restrict__ embed,
    const int* __restrict__ rcount, const int* __restrict__ rlist,
    int* __restrict__ idx_out) {
    __shared__ double xsh[256];
    __shared__ double ms[256];
    __shared__ int    ks[256];
    int cnt = *rcount; if (cnt > RCAP) cnt = RCAP;
    const int t = threadIdx.x;
    for (int li = blockIdx.x; li < cnt; li += gridDim.x) {
        int n = rlist[li];
        int b = n >> 10, hw = n & 1023;
        __syncthreads();
        xsh[t] = (double)inp[(((size_t)b << 8) + t) * 1024 + hw];
        __syncthreads();
        double s0 = 0.0, s1 = 0.0, s2 = 0.0, s3 = 0.0;
        const float* eb = embed + t;
#pragma unroll 4
        for (int c = 0; c < 256; ++c) {
            double xc2 = 2.0 * xsh[c];
            const float* er = eb + ((size_t)c << 10);
            double e0 = (double)er[0];
            double e1 = (double)er[256];
            double e2 = (double)er[512];
            double e3 = (double)er[768];
            s0 = fma(e0, e0 - xc2, s0);
            s1 = fma(e1, e1 - xc2, s1);
            s2 = fma(e2, e2 - xc2, s2);
            s3 = fma(e3, e3 - xc2, s3);
        }
        double bv = s0; int bk = t;
        if (s1 < bv) { bv = s1; bk = t + 256; }
        if (s2 < bv) { bv = s2; bk = t + 512; }
        if (s3 < bv) { bv = s3; bk = t + 768; }
        ms[t] = bv; ks[t] = bk;
        __syncthreads();
        if (t < 32) {
            double av = ms[t]; int ak = ks[t];
            for (int u = t + 32; u < 256; u += 32)
                if (ms[u] < av || (ms[u] == av && ks[u] < ak)) { av = ms[u]; ak = ks[u]; }
            ms[t] = av; ks[t] = ak;
        }
        __syncthreads();
        if (t == 0) {
            double av = ms[0]; int ak = ks[0];
            for (int u = 1; u < 32; ++u)
                if (ms[u] < av || (ms[u] == av && ks[u] < ak)) { av = ms[u]; ak = ks[u]; }
            idx_out[n] = ak;
        }
        __syncthreads();
    }
}

__global__ __launch_bounds__(256) void kq_gather(
    const float* __restrict__ inp, const float* __restrict__ embed,
    const int* __restrict__ idx, float* __restrict__ out0,
    float* __restrict__ lossAcc) {
    int bx = blockIdx.x;
    int b = bx >> 4, cg = bx & 15;
    int t = threadIdx.x;
    int hw4 = t << 2;
    int4 iv = *(const int4*)(idx + (b << 10) + hw4);
    float lsum = 0.f;
    for (int cl = 0; cl < 16; ++cl) {
        int c = cg * 16 + cl;
        size_t off = (((size_t)b << 8) + c) * 1024 + hw4;
        float4 x = *(const float4*)(inp + off);
        const float* er = embed + ((size_t)c << 10);
        float4 q = make_float4(er[iv.x], er[iv.y], er[iv.z], er[iv.w]);
        *(float4*)(out0 + off) = q;
        float dx = q.x - x.x, dy = q.y - x.y, dz = q.z - x.z, dw = q.w - x.w;
        lsum = fmaf(dx, dx, lsum); lsum = fmaf(dy, dy, lsum);
        lsum = fmaf(dz, dz, lsum); lsum = fmaf(dw, dw, lsum);
    }
    __shared__ float red[256];
    red[t] = lsum; __syncthreads();
    for (int s2 = 128; s2 > 0; s2 >>= 1) {
        if (t < s2) red[t] += red[t + s2];
        __syncthreads();
    }
    if (t == 0) atomicAdd(lossAcc, red[0]);
}

__global__ void kq_finalize(const int* __restrict__ idx, const float* __restrict__ lossAcc,
                            float* __restrict__ onehot, float* __restrict__ lossOut) {
    int n = blockIdx.x * 256 + threadIdx.x;
    onehot[(size_t)n * 1024 + idx[n]] = 1.0f;
    if (n == 0) *lossOut = 1.25f * (*lossAcc) / 8388608.0f;
}

extern "C" void kernel_launch(void* const* d_in, const int* in_sizes, int n_in,
                              void* d_out, int out_size, void* d_ws, size_t ws_size,
                              hipStream_t stream) {
    const float* inp   = (const float*)d_in[0];
    const float* embed = (const float*)d_in[1];
    float* out0    = (float*)d_out;
    float* lossOut = (float*)d_out + OUT0;
    float* onehot  = (float*)d_out + OUT0 + 1;

    // ws layout (float-indexed):
    // [0] lossAcc | [1] rcount | [2] doneCnt | [3] pad | [4..1028) enorm |
    // [1028..+32768) idx | [33796..+8192) rlist | [41988..+32768) xnorm |
    // [74756..) Ahi(4194304 us) Alo(4194304 us) Bcat(262144 us)
    //           gm1(262144 f) gm2(262144 f) gk(262144 i)
    float* wsf     = (float*)d_ws;
    float* lossAcc = wsf;
    int*   rcount  = (int*)wsf + 1;
    int*   doneCnt = (int*)wsf + 2;
    float* enorm   = wsf + 4;
    int*   idxbuf  = (int*)wsf + 1028;
    int*   rlist   = (int*)wsf + 1028 + NROWS;
    float* xnorm   = wsf + 41988;
    unsigned short* Ahi  = (unsigned short*)(wsf + 74756);
    unsigned short* Alo  = (unsigned short*)(wsf + 74756 + 4194304);
    unsigned short* Bcat = (unsigned short*)(wsf + 74756 + 8388608);
    float* gm1 = wsf + 74756 + 8388608 + 262144;
    float* gm2 = gm1 + 262144;
    int*   gk  = (int*)(gm2 + 262144);

    const size_t NEED = (size_t)(74756 + 8388608 + 262144 + 3 * 262144) * 4;

    if (ws_size >= NEED) {
        // zero header: lossAcc, rcount, doneCnt, pad, enorm (4112 B)
        hipMemsetAsync(wsf, 0, 1028 * sizeof(float), stream);
        kq_prep   <<<576,  256, 0, stream>>>(inp, embed, Ahi, Alo, Bcat, enorm, xnorm);
        kq_gemm   <<<2048, 256, 0, stream>>>(Ahi, Alo, Bcat, enorm, gm1, gm2, gk);
        kq_finale <<<512,  256, 0, stream>>>(inp, embed, gm1, gm2, gk, xnorm,
                                             lossAcc, doneCnt, out0, onehot, lossOut);
    } else {
        hipMemsetAsync(onehot, 0, (size_t)NROWS * 1024 * sizeof(float), stream);
        kq_norms   <<<4,    256, 0, stream>>>(embed, enorm, lossAcc, rcount);
        kq_argmin  <<<512,  256, 0, stream>>>(inp, embed, enorm, idxbuf, rcount, rlist);
        kq_refine  <<<1024, 256, 0, stream>>>(inp, embed, rcount, rlist, idxbuf);
        kq_gather  <<<512,  256, 0, stream>>>(inp, embed, idxbuf, out0, lossAcc);
        kq_finalize<<<128,  256, 0, stream>>>(idxbuf, lossAcc, onehot, lossOut);
    }
}

// Round 8
// 364.139 us; speedup vs baseline: 1.0706x; 1.0706x over previous
//
#include <hip/hip_runtime.h>
#include <stdint.h>

// FeatureQuantizer: VQ-VAE quantize forward.
// inputs (32,256,32,32) f32, embed (256,1024) f32.
// out = [ quantize (B,C,H,W) 8388608 | loss 1 | onehot (32768,1024) 33554432 ] f32
//
// R7 fix: __builtin_nontemporal_store requires a native vector type, not
// HIP_vector_type float4 -> use ext_vector_type floatx4 for output streams.
// Structure (from R7 theory): prep(576) -> gemm(2048, R4 3-buffer) ->
// combine(128) -> refine(1024) -> out(2560, float4 nontemporal).

#define NROWS 32768
#define OUT0  8388608
#define TAU   0.01f
#define RCAP  8192

typedef __attribute__((ext_vector_type(8))) short short8;
typedef __attribute__((ext_vector_type(4))) float floatx4;

__device__ __forceinline__ void gload16(const void* g, void* l) {
    __builtin_amdgcn_global_load_lds(
        (const __attribute__((address_space(1))) void*)g,
        (__attribute__((address_space(3))) void*)l, 16, 0, 0);
}
__device__ __forceinline__ unsigned short bf16_rn(float x) {
    union { float f; unsigned u; } v; v.f = x;
    unsigned r = v.u + 0x7FFF + ((v.u >> 16) & 1);
    return (unsigned short)(r >> 16);
}
__device__ __forceinline__ float bf16_f(unsigned short h) {
    union { unsigned u; float f; } v; v.u = ((unsigned)h) << 16;
    return v.f;
}

// ---- P: fused prep. blocks [0,512): inputs->Ahi/Alo/xnorm ; [512,576): embed->Bcat/enorm
__global__ __launch_bounds__(256) void kq_prep(
    const float* __restrict__ inp, const float* __restrict__ embed,
    unsigned short* __restrict__ Ahi, unsigned short* __restrict__ Alo,
    unsigned short* __restrict__ Bcat, float* __restrict__ enorm,
    float* __restrict__ xnorm) {
    __shared__ float ls[64][65];
    __shared__ float sums[16][64];
    int t = threadIdx.x;
    if (blockIdx.x >= 512) {
        // ---- embed path ----
        int bx = blockIdx.x - 512;    // 64 = 16 kt * 4 ct
        int ct = bx & 3, kt = bx >> 2;
        int c0 = ct * 64, k0 = kt * 64;
#pragma unroll
        for (int p = 0; p < 16; ++p) {
            int cl = p * 4 + (t >> 6);
            int kl = t & 63;
            ls[cl][kl] = embed[(size_t)(c0 + cl) * 1024 + k0 + kl];
        }
        __syncthreads();
#pragma unroll
        for (int p = 0; p < 16; ++p) {
            int kl = p * 4 + (t >> 6);
            int c = t & 63;
            float x = ls[c][kl];
            unsigned short hi = bf16_rn(x);
            unsigned short lo = bf16_rn(x - bf16_f(hi));
            size_t base = (size_t)(k0 + kl) * 512;
            Bcat[base + c0 + c]       = hi;
            Bcat[base + 256 + c0 + c] = lo;
        }
        if (t < 64) {
            float s = 0.f;
#pragma unroll 8
            for (int c = 0; c < 64; ++c) {
                float e = ls[c][t];
                s = fmaf(e, e, s);
            }
            atomicAdd(enorm + k0 + t, s);
        }
        return;
    }
    // ---- inputs path ----
    int bx = blockIdx.x;          // 512 = 32 b * 16 hwt
    int hwt = bx & 15;
    int b   = bx >> 4;
    int hw0 = hwt * 64;
    float xpart[4] = {0.f, 0.f, 0.f, 0.f};
    for (int ct = 0; ct < 4; ++ct) {
        const float* src = inp + ((size_t)b << 18) + (size_t)(ct * 64) * 1024 + hw0;
        __syncthreads();          // ls reuse across ct
#pragma unroll
        for (int p = 0; p < 4; ++p) {
            int cl = (t >> 4) + p * 16;
            int h4 = (t & 15) << 2;
            float4 v = *(const float4*)(src + (size_t)cl * 1024 + h4);
            ls[cl][h4] = v.x; ls[cl][h4+1] = v.y; ls[cl][h4+2] = v.z; ls[cl][h4+3] = v.w;
        }
        __syncthreads();
#pragma unroll
        for (int p = 0; p < 4; ++p) {
            int hwl = p * 16 + (t >> 4);
            int c4 = (t & 15) << 2;
            float x0 = ls[c4][hwl], x1 = ls[c4+1][hwl];
            float x2 = ls[c4+2][hwl], x3 = ls[c4+3][hwl];
            ushort4 hi, lo;
            hi.x = bf16_rn(x0); lo.x = bf16_rn(x0 - bf16_f(hi.x));
            hi.y = bf16_rn(x1); lo.y = bf16_rn(x1 - bf16_f(hi.y));
            hi.z = bf16_rn(x2); lo.z = bf16_rn(x2 - bf16_f(hi.z));
            hi.w = bf16_rn(x3); lo.w = bf16_rn(x3 - bf16_f(hi.w));
            size_t n = ((size_t)b << 10) + hw0 + hwl;
            *(ushort4*)(Ahi + n * 256 + ct * 64 + c4) = hi;
            *(ushort4*)(Alo + n * 256 + ct * 64 + c4) = lo;
            xpart[p] = fmaf(x0, x0, xpart[p]);
            xpart[p] = fmaf(x1, x1, xpart[p]);
            xpart[p] = fmaf(x2, x2, xpart[p]);
            xpart[p] = fmaf(x3, x3, xpart[p]);
        }
    }
    __syncthreads();
#pragma unroll
    for (int p = 0; p < 4; ++p)
        sums[t & 15][p * 16 + (t >> 4)] = xpart[p];
    __syncthreads();
    if (t < 64) {
        float s = 0.f;
#pragma unroll
        for (int j = 0; j < 16; ++j) s += sums[j][t];
        xnorm[((size_t)b << 10) + hw0 + t] = s;
    }
}

// ---------------- K2: MFMA dist-GEMM + per-block top-2 argmin ----------------
// R4 structure: 3 LDS buffers; phase1 {A_hi, B_hi, B_lo} 64 MFMA/stage;
// phase2 {A_lo, B_hi} 32 MFMA/stage. Plain launch_bounds: no spill (VGPR ~112).
__global__ __launch_bounds__(256) void kq_gemm(
    const unsigned short* __restrict__ Ahi, const unsigned short* __restrict__ Alo,
    const unsigned short* __restrict__ Bcat, const float* __restrict__ enorm,
    float* __restrict__ gm1, float* __restrict__ gm2, int* __restrict__ gk) {

    __shared__ __align__(16) unsigned short As[128 * 64];    // 16 KB
    __shared__ __align__(16) unsigned short Bs[128 * 64];    // 16 KB
    __shared__ __align__(16) unsigned short Bs2[128 * 64];   // 16 KB
    __shared__ float cm1[2][128];
    __shared__ float cm2[2][128];
    __shared__ int   ckk[2][128];

    const int t = threadIdx.x;
    const int lane = t & 63, w = t >> 6;
    const int wm = w >> 1, wn = w & 1;
    // XCD swizzle: same rb -> same blockIdx%8 -> same XCD L2 holds the A-tile
    const int cb = blockIdx.x >> 8, rb = blockIdx.x & 255;

    const int l7 = lane & 7, l8 = lane >> 3;
    const int swz = l7 ^ l8;              // global-side k-group permutation

    floatx4 acc[4][4];
#pragma unroll
    for (int i = 0; i < 4; ++i)
#pragma unroll
        for (int j = 0; j < 4; ++j) acc[i][j] = (floatx4){0.f, 0.f, 0.f, 0.f};

    unsigned short* AsW  = As  + (w * 32) * 64;
    unsigned short* BsW  = Bs  + (w * 32) * 64;
    unsigned short* Bs2W = Bs2 + (w * 32) * 64;

    // ---- phase 1: A_hi x {B_hi, B_lo} ----
    for (int ci = 0; ci < 4; ++ci) {
        const unsigned short* Asrc = Ahi + (size_t)ci * 64;
        const unsigned short* B1 = Bcat + (size_t)ci * 64;          // e_hi chunk
        const unsigned short* B2 = Bcat + (size_t)(4 + ci) * 64;    // e_lo chunk
        __syncthreads();
#pragma unroll
        for (int i = 0; i < 4; ++i) {
            int arow = rb * 128 + w * 32 + i * 8 + l8;
            gload16(Asrc + (size_t)arow * 256 + swz * 8, AsW + (i * 8) * 64);
            int brow = cb * 128 + w * 32 + i * 8 + l8;
            gload16(B1 + (size_t)brow * 512 + swz * 8, BsW + (i * 8) * 64);
            gload16(B2 + (size_t)brow * 512 + swz * 8, Bs2W + (i * 8) * 64);
        }
        __syncthreads();
#pragma unroll
        for (int kk = 0; kk < 2; ++kk) {
            short8 af[4], bf[4], bf2[4];
            int pg = (kk * 4 + (lane >> 4)) ^ l7;
#pragma unroll
            for (int i = 0; i < 4; ++i) {
                int m = wm * 64 + i * 16 + (lane & 15);
                af[i] = *(const short8*)(As + m * 64 + pg * 8);
                int n = wn * 64 + i * 16 + (lane & 15);
                bf[i]  = *(const short8*)(Bs  + n * 64 + pg * 8);
                bf2[i] = *(const short8*)(Bs2 + n * 64 + pg * 8);
            }
#pragma unroll
            for (int i = 0; i < 4; ++i)
#pragma unroll
                for (int j = 0; j < 4; ++j) {
                    acc[i][j] = __builtin_amdgcn_mfma_f32_16x16x32_bf16(
                        af[i], bf[j], acc[i][j], 0, 0, 0);
                    acc[i][j] = __builtin_amdgcn_mfma_f32_16x16x32_bf16(
                        af[i], bf2[j], acc[i][j], 0, 0, 0);
                }
        }
    }
    // ---- phase 2: A_lo x B_hi ----
    for (int ci = 0; ci < 4; ++ci) {
        const unsigned short* Asrc = Alo + (size_t)ci * 64;
        const unsigned short* B1 = Bcat + (size_t)ci * 64;
        __syncthreads();
#pragma unroll
        for (int i = 0; i < 4; ++i) {
            int arow = rb * 128 + w * 32 + i * 8 + l8;
            gload16(Asrc + (size_t)arow * 256 + swz * 8, AsW + (i * 8) * 64);
            int brow = cb * 128 + w * 32 + i * 8 + l8;
            gload16(B1 + (size_t)brow * 512 + swz * 8, BsW + (i * 8) * 64);
        }
        __syncthreads();
#pragma unroll
        for (int kk = 0; kk < 2; ++kk) {
            short8 af[4], bf[4];
            int pg = (kk * 4 + (lane >> 4)) ^ l7;
#pragma unroll
            for (int i = 0; i < 4; ++i) {
                int m = wm * 64 + i * 16 + (lane & 15);
                af[i] = *(const short8*)(As + m * 64 + pg * 8);
                int n = wn * 64 + i * 16 + (lane & 15);
                bf[i] = *(const short8*)(Bs + n * 64 + pg * 8);
            }
#pragma unroll
            for (int i = 0; i < 4; ++i)
#pragma unroll
                for (int j = 0; j < 4; ++j)
                    acc[i][j] = __builtin_amdgcn_mfma_f32_16x16x32_bf16(
                        af[i], bf[j], acc[i][j], 0, 0, 0);
        }
    }

    // ---- epilogue: score = enorm[k] - 2*dot; top-2 per row ----
    float en[4];
#pragma unroll
    for (int j = 0; j < 4; ++j)
        en[j] = enorm[cb * 128 + wn * 64 + j * 16 + (lane & 15)];

    const int q4 = lane >> 4;
#pragma unroll
    for (int i = 0; i < 4; ++i) {
#pragma unroll
        for (int r = 0; r < 4; ++r) {
            float m1 = 3.4e38f, m2 = 3.4e38f; int k1 = 0x7fffffff;
#pragma unroll
            for (int j = 0; j < 4; ++j) {
                float s = fmaf(-2.f, acc[i][j][r], en[j]);
                int kg = cb * 128 + wn * 64 + j * 16 + (lane & 15);
                if (s < m1) { m2 = m1; m1 = s; k1 = kg; }
                else if (s < m2) m2 = s;
            }
#pragma unroll
            for (int d = 1; d < 16; d <<= 1) {   // 16-lane butterfly (cols)
                float om1 = __shfl_xor(m1, d, 64);
                float om2 = __shfl_xor(m2, d, 64);
                int   ok1 = __shfl_xor(k1, d, 64);
                if (om1 < m1 || (om1 == m1 && ok1 < k1)) {
                    m2 = fminf(m1, om2); m1 = om1; k1 = ok1;
                } else {
                    m2 = fminf(m2, om1);
                }
            }
            if ((lane & 15) == 0) {
                int row = wm * 64 + i * 16 + q4 * 4 + r;
                cm1[wn][row] = m1; cm2[wn][row] = m2; ckk[wn][row] = k1;
            }
        }
    }
    __syncthreads();
    if (t < 128) {
        float a1 = cm1[0][t], a2 = cm2[0][t]; int ak = ckk[0][t];
        float b1 = cm1[1][t], b2 = cm2[1][t]; int bk = ckk[1][t];
        if (b1 < a1 || (b1 == a1 && bk < ak)) { a2 = fminf(a1, b2); a1 = b1; ak = bk; }
        else { a2 = fminf(a2, b1); }
        size_t o = (size_t)cb * NROWS + (size_t)rb * 128 + t;
        gm1[o] = a1; gm2[o] = a2; gk[o] = ak;
    }
}

// ------- K2c: combine 8 column-block candidates per row + loss accumulate ----
__global__ __launch_bounds__(256) void kq_combine(
    const float* __restrict__ gm1, const float* __restrict__ gm2,
    const int* __restrict__ gk, const float* __restrict__ xnorm,
    int* __restrict__ idx_out, int* __restrict__ rcount, int* __restrict__ rlist,
    float* __restrict__ lossAcc) {
    int t = threadIdx.x;
    int r = blockIdx.x * 256 + t;   // 128 blocks
    float a1 = gm1[r], a2 = gm2[r]; int ak = gk[r];
#pragma unroll
    for (int cbi = 1; cbi < 8; ++cbi) {
        size_t o = (size_t)cbi * NROWS + r;
        float b1 = gm1[o], b2 = gm2[o]; int bk = gk[o];
        if (b1 < a1 || (b1 == a1 && bk < ak)) { a2 = fminf(a1, b2); a1 = b1; ak = bk; }
        else { a2 = fminf(a2, b1); }
    }
    idx_out[r] = ak;
    if (a2 - a1 < TAU) {
        int pos = atomicAdd(rcount, 1);
        if (pos < RCAP) rlist[pos] = r;
    }
    __shared__ float red[256];
    red[t] = a1 + xnorm[r];
    __syncthreads();
    for (int s2 = 128; s2 > 0; s2 >>= 1) {
        if (t < s2) red[t] += red[t + s2];
        __syncthreads();
    }
    if (t == 0) atomicAdd(lossAcc, red[0]);
}

// ---------------- K2b: fp64 re-resolve of near-tie rows ----------------
__global__ __launch_bounds__(256) void kq_refine(
    const float* __restrict__ inp, const float* __restrict__ embed,
    const int* __restrict__ rcount, const int* __restrict__ rlist,
    int* __restrict__ idx_out) {
    __shared__ double xsh[256];
    __shared__ double ms[256];
    __shared__ int    ks[256];
    int cnt = *rcount; if (cnt > RCAP) cnt = RCAP;
    const int t = threadIdx.x;
    for (int li = blockIdx.x; li < cnt; li += gridDim.x) {
        int n = rlist[li];
        int b = n >> 10, hw = n & 1023;
        __syncthreads();
        xsh[t] = (double)inp[(((size_t)b << 8) + t) * 1024 + hw];
        __syncthreads();
        double s0 = 0.0, s1 = 0.0, s2 = 0.0, s3 = 0.0;
        const float* eb = embed + t;
#pragma unroll 4
        for (int c = 0; c < 256; ++c) {
            double xc2 = 2.0 * xsh[c];
            const float* er = eb + ((size_t)c << 10);
            double e0 = (double)er[0];
            double e1 = (double)er[256];
            double e2 = (double)er[512];
            double e3 = (double)er[768];
            s0 = fma(e0, e0 - xc2, s0);
            s1 = fma(e1, e1 - xc2, s1);
            s2 = fma(e2, e2 - xc2, s2);
            s3 = fma(e3, e3 - xc2, s3);
        }
        double bv = s0; int bk = t;
        if (s1 < bv) { bv = s1; bk = t + 256; }
        if (s2 < bv) { bv = s2; bk = t + 512; }
        if (s3 < bv) { bv = s3; bk = t + 768; }
        ms[t] = bv; ks[t] = bk;
        __syncthreads();
        if (t < 32) {
            double av = ms[t]; int ak = ks[t];
            for (int u = t + 32; u < 256; u += 32)
                if (ms[u] < av || (ms[u] == av && ks[u] < ak)) { av = ms[u]; ak = ks[u]; }
            ms[t] = av; ks[t] = ak;
        }
        __syncthreads();
        if (t == 0) {
            double av = ms[0]; int ak = ks[0];
            for (int u = 1; u < 32; ++u)
                if (ms[u] < av || (ms[u] == av && ks[u] < ak)) { av = ms[u]; ak = ks[u]; }
            idx_out[n] = ak;
        }
        __syncthreads();
    }
}

// ---- K3: outputs. blocks [0,512): quantize gather; [512,2560): onehot ------
__global__ __launch_bounds__(256) void kq_out(
    const float* __restrict__ embed, const int* __restrict__ idx,
    const float* __restrict__ lossAcc, float* __restrict__ out0,
    float* __restrict__ onehot, float* __restrict__ lossOut) {
    int bx = blockIdx.x;
    int t = threadIdx.x;
    if (bx < 512) {
        int b = bx >> 4, cg = bx & 15;
        int hw4 = t << 2;
        int4 iv = *(const int4*)(idx + (b << 10) + hw4);
#pragma unroll 4
        for (int cl = 0; cl < 16; ++cl) {
            int c = cg * 16 + cl;
            size_t off = (((size_t)b << 8) + c) * 1024 + hw4;
            const float* er = embed + ((size_t)c << 10);
            floatx4 q = {er[iv.x], er[iv.y], er[iv.z], er[iv.w]};
            __builtin_nontemporal_store(q, (floatx4*)(out0 + off));
        }
        if (bx == 0 && t == 0) *lossOut = 1.25f * (*lossAcc) / 8388608.0f;
    } else {
        int r0 = (bx - 512) << 4;        // 16 rows per block
        __shared__ int lidx[16];
        if (t < 16) lidx[t] = idx[r0 + t];
        __syncthreads();
        float* dst = onehot + (size_t)r0 * 1024 + (t << 2);
#pragma unroll
        for (int row = 0; row < 16; ++row) {
            int k = lidx[row];
            floatx4 v = {0.f, 0.f, 0.f, 0.f};
            if ((k >> 2) == t) v[k & 3] = 1.0f;
            __builtin_nontemporal_store(v, (floatx4*)(dst + (size_t)row * 1024));
        }
    }
}

// ======== Fallback path (ws too small for MFMA scratch) ========
__global__ void kq_norms(const float* __restrict__ embed, float* __restrict__ enorm,
                         float* __restrict__ lossAcc, int* __restrict__ rcount) {
    int k = blockIdx.x * 256 + threadIdx.x;
    float s = 0.f;
    for (int c = 0; c < 256; ++c) {
        float e = embed[(c << 10) + k];
        s = fmaf(e, e, s);
    }
    enorm[k] = s;
    if (k == 0) { *lossAcc = 0.f; *rcount = 0; }
}

__global__ __launch_bounds__(256) void kq_argmin(
    const float* __restrict__ inp, const float* __restrict__ embed,
    const float* __restrict__ enorm, int* __restrict__ idx_out,
    int* __restrict__ rcount, int* __restrict__ rlist) {
    __shared__ float xs[32][64];
    __shared__ float es[32][256];
    const int t  = threadIdx.x;
    const int tx = t & 31, ty = t >> 5;
    const int bi = blockIdx.x;
    const int b   = bi >> 4;
    const int hw0 = (bi & 15) << 6;
    const float* xbase = inp + ((size_t)b << 18) + hw0;
    float m1[8], m2[8]; int bk[8];
#pragma unroll
    for (int i = 0; i < 8; ++i) { m1[i] = 3.4e38f; m2[i] = 3.4e38f; bk[i] = 0; }
    for (int kt = 0; kt < 4; ++kt) {
        float acc[8][8];
#pragma unroll
        for (int i = 0; i < 8; ++i)
#pragma unroll
            for (int j = 0; j < 8; ++j) acc[i][j] = 0.f;
        for (int cc = 0; cc < 8; ++cc) {
            __syncthreads();
            {
                int r4 = (t & 15) << 2;
                int cbk = t >> 4;
#pragma unroll
                for (int p = 0; p < 2; ++p) {
                    int cl = cbk + (p << 4);
                    float4 v = *(const float4*)(xbase + (size_t)(cc * 32 + cl) * 1024 + r4);
                    *(float4*)&xs[cl][r4] = v;
                }
            }
            {
                int k4 = (t & 63) << 2;
                int cbk = t >> 6;
#pragma unroll
                for (int p = 0; p < 8; ++p) {
                    int cl = cbk + (p << 2);
                    float4 v = *(const float4*)(embed + (size_t)(cc * 32 + cl) * 1024 + kt * 256 + k4);
                    *(float4*)&es[cl][k4] = v;
                }
            }
            __syncthreads();
#pragma unroll 4
            for (int c = 0; c < 32; ++c) {
                float4 xa = *(const float4*)&xs[c][ty << 3];
                float4 xb = *(const float4*)&xs[c][(ty << 3) + 4];
                float4 ea = *(const float4*)&es[c][tx << 3];
                float4 eb = *(const float4*)&es[c][(tx << 3) + 4];
                float xv[8] = {xa.x, xa.y, xa.z, xa.w, xb.x, xb.y, xb.z, xb.w};
                float ev[8] = {ea.x, ea.y, ea.z, ea.w, eb.x, eb.y, eb.z, eb.w};
#pragma unroll
                for (int i = 0; i < 8; ++i)
#pragma unroll
                    for (int j = 0; j < 8; ++j)
                        acc[i][j] = fmaf(xv[i], ev[j], acc[i][j]);
            }
        }
        const float* en = enorm + kt * 256 + (tx << 3);
        float4 en0 = *(const float4*)en;
        float4 en1 = *(const float4*)(en + 4);
        float env[8] = {en0.x, en0.y, en0.z, en0.w, en1.x, en1.y, en1.z, en1.w};
        int kbase = kt * 256 + (tx << 3);
#pragma unroll
        for (int i = 0; i < 8; ++i) {
#pragma unroll
            for (int j = 0; j < 8; ++j) {
                float s = fmaf(-2.f, acc[i][j], env[j]);
                if (s < m1[i]) { m2[i] = m1[i]; m1[i] = s; bk[i] = kbase + j; }
                else if (s < m2[i]) m2[i] = s;
            }
        }
    }
    __syncthreads();
    float* r1 = &es[0][0];
    float* r2 = r1 + 2048;
    int*   rb = (int*)(r2 + 2048);
#pragma unroll
    for (int i = 0; i < 8; ++i) {
        int row = (ty << 3) + i;
        r1[row * 32 + tx] = m1[i];
        r2[row * 32 + tx] = m2[i];
        rb[row * 32 + tx] = bk[i];
    }
    __syncthreads();
    if (t < 64) {
        int row = t;
        float a1 = r1[row * 32], a2 = r2[row * 32];
        int   ab = rb[row * 32];
        for (int u = 1; u < 32; ++u) {
            float b1 = r1[row * 32 + u], b2 = r2[row * 32 + u];
            int   bb = rb[row * 32 + u];
            if (b1 < a1) { a2 = fminf(a1, b2); a1 = b1; ab = bb; }
            else         { a2 = fminf(a2, b1); }
        }
        int n = (b << 10) + hw0 + row;
        idx_out[n] = ab;
        if (a2 - a1 < TAU) {
            int pos = atomicAdd(rcount, 1);
            if (pos < RCAP) rlist[pos] = n;
        }
    }
}

__global__ __launch_bounds__(256) void kq_gather(
    const float* __restrict__ inp, const float* __restrict__ embed,
    const int* __restrict__ idx, float* __restrict__ out0,
    float* __restrict__ lossAcc) {
    int bx = blockIdx.x;
    int b = bx >> 4, cg = bx & 15;
    int t = threadIdx.x;
    int hw4 = t << 2;
    int4 iv = *(const int4*)(idx + (b << 10) + hw4);
    float lsum = 0.f;
    for (int cl = 0; cl < 16; ++cl) {
        int c = cg * 16 + cl;
        size_t off = (((size_t)b << 8) + c) * 1024 + hw4;
        float4 x = *(const float4*)(inp + off);
        const float* er = embed + ((size_t)c << 10);
        float4 q = make_float4(er[iv.x], er[iv.y], er[iv.z], er[iv.w]);
        *(float4*)(out0 + off) = q;
        float dx = q.x - x.x, dy = q.y - x.y, dz = q.z - x.z, dw = q.w - x.w;
        lsum = fmaf(dx, dx, lsum); lsum = fmaf(dy, dy, lsum);
        lsum = fmaf(dz, dz, lsum); lsum = fmaf(dw, dw, lsum);
    }
    __shared__ float red[256];
    red[t] = lsum; __syncthreads();
    for (int s2 = 128; s2 > 0; s2 >>= 1) {
        if (t < s2) red[t] += red[t + s2];
        __syncthreads();
    }
    if (t == 0) atomicAdd(lossAcc, red[0]);
}

__global__ void kq_finalize(const int* __restrict__ idx, const float* __restrict__ lossAcc,
                            float* __restrict__ onehot, float* __restrict__ lossOut) {
    int n = blockIdx.x * 256 + threadIdx.x;
    onehot[(size_t)n * 1024 + idx[n]] = 1.0f;
    if (n == 0) *lossOut = 1.25f * (*lossAcc) / 8388608.0f;
}

extern "C" void kernel_launch(void* const* d_in, const int* in_sizes, int n_in,
                              void* d_out, int out_size, void* d_ws, size_t ws_size,
                              hipStream_t stream) {
    const float* inp   = (const float*)d_in[0];
    const float* embed = (const float*)d_in[1];
    float* out0    = (float*)d_out;
    float* lossOut = (float*)d_out + OUT0;
    float* onehot  = (float*)d_out + OUT0 + 1;

    // ws layout (float-indexed):
    // [0] lossAcc | [1] rcount | [2] pad | [3] pad | [4..1028) enorm |
    // [1028..+32768) idx | [33796..+8192) rlist | [41988..+32768) xnorm |
    // [74756..) Ahi(4194304 us) Alo(4194304 us) Bcat(262144 us)
    //           gm1(262144 f) gm2(262144 f) gk(262144 i)
    float* wsf     = (float*)d_ws;
    float* lossAcc = wsf;
    int*   rcount  = (int*)wsf + 1;
    float* enorm   = wsf + 4;
    int*   idxbuf  = (int*)wsf + 1028;
    int*   rlist   = (int*)wsf + 1028 + NROWS;
    float* xnorm   = wsf + 41988;
    unsigned short* Ahi  = (unsigned short*)(wsf + 74756);
    unsigned short* Alo  = (unsigned short*)(wsf + 74756 + 4194304);
    unsigned short* Bcat = (unsigned short*)(wsf + 74756 + 8388608);
    float* gm1 = wsf + 74756 + 8388608 + 262144;
    float* gm2 = gm1 + 262144;
    int*   gk  = (int*)(gm2 + 262144);

    const size_t NEED = (size_t)(74756 + 8388608 + 262144 + 3 * 262144) * 4;

    if (ws_size >= NEED) {
        // zero header: lossAcc, rcount, pads, enorm (4112 B)
        (void)hipMemsetAsync(wsf, 0, 1028 * sizeof(float), stream);
        kq_prep    <<<576,  256, 0, stream>>>(inp, embed, Ahi, Alo, Bcat, enorm, xnorm);
        kq_gemm    <<<2048, 256, 0, stream>>>(Ahi, Alo, Bcat, enorm, gm1, gm2, gk);
        kq_combine <<<128,  256, 0, stream>>>(gm1, gm2, gk, xnorm, idxbuf,
                                              rcount, rlist, lossAcc);
        kq_refine  <<<1024, 256, 0, stream>>>(inp, embed, rcount, rlist, idxbuf);
        kq_out     <<<2560, 256, 0, stream>>>(embed, idxbuf, lossAcc,
                                              out0, onehot, lossOut);
    } else {
        (void)hipMemsetAsync(onehot, 0, (size_t)NROWS * 1024 * sizeof(float), stream);
        kq_norms   <<<4,    256, 0, stream>>>(embed, enorm, lossAcc, rcount);
        kq_argmin  <<<512,  256, 0, stream>>>(inp, embed, enorm, idxbuf, rcount, rlist);
        kq_refine  <<<1024, 256, 0, stream>>>(inp, embed, rcount, rlist, idxbuf);
        kq_gather  <<<512,  256, 0, stream>>>(inp, embed, idxbuf, out0, lossAcc);
        kq_finalize<<<128,  256, 0, stream>>>(idxbuf, lossAcc, onehot, lossOut);
    }
}